// Round 3
// baseline (399.408 us; speedup 1.0000x reference)
//
#include <hip/hip_runtime.h>

#define BB 4
#define SS 2048
#define DD 1024
#define HH 16
#define DKC 64
#define MT (BB*SS)   // 8192 rows total
#define NX (MT*DD)   // 8388608
#define NW (DD*DD)   // 1048576

typedef _Float16 f16x8 __attribute__((ext_vector_type(8)));
typedef _Float16 f16x4 __attribute__((ext_vector_type(4)));
typedef float f32x4 __attribute__((ext_vector_type(4)));
typedef int   i32x4 __attribute__((ext_vector_type(4)));

// ---------------- QKV projection: Y = X @ W^T + b, fp32 in / f16 out ----------------
// R12: back to the R0 single-buffer reg-staged structure (16 KB LDS -> 8
// blocks/CU, thread-capped; measured best across R0/R1/R2) with two additions:
//  (a) fp32->f16 conversion FUSED into the staging commit (cvt_all kernel
//      deleted; X/W read as fp32, L3 absorbs the re-reads). RTE scalar casts
//      to keep numerics identical to the old cvt_all.
//  (b) conflict-free LDS: ds_write at physical chunk (t&3)^((t>>3)&3) (= chunk
//      c xor (row>>1)&3), frag read at q^((r>>1)&3). R0's linear layout was an
//      ~8-way read conflict (64B rows alias banks every 2 rows); at 8 blocks/CU
//      the LDS pipe is shared, so the serialization was real bandwidth lost.
// Cross-iteration latency tolerance: prefetch(k+1) issued after the commit
// barrier; its vmcnt wait lands in the NEXT iteration's commit.
__global__ __launch_bounds__(256) void gemm_qkv(const float* __restrict__ xq,
                                                const float* __restrict__ xk,
                                                const float* __restrict__ xv,
                                                const float* __restrict__ wq,
                                                const float* __restrict__ wk,
                                                const float* __restrict__ wv,
                                                const float* __restrict__ b0,
                                                const float* __restrict__ b1,
                                                const float* __restrict__ b2,
                                                _Float16* __restrict__ Pj) {
  const int z = blockIdx.z;
  const float* A = (z == 0) ? xq : ((z == 1) ? xk : xv);
  const float* W = (z == 0) ? wq : ((z == 1) ? wk : wv);
  const float* bias = (z == 0) ? b0 : ((z == 1) ? b1 : b2);
  _Float16* out = Pj + (size_t)z * MT * DD;

  const int m0 = blockIdx.x * 128;   // m fastest -> XCD round-robin over m
  const int n0 = blockIdx.y * 128;
  const int t = threadIdx.x;
  const int lane = t & 63;
  const int wave = t >> 6;
  const int q = lane >> 4, r = lane & 15;
  const int wm = (wave & 1) * 64, wn = (wave >> 1) * 64;

  __shared__ __align__(16) _Float16 sA[128 * 32];
  __shared__ __align__(16) _Float16 sB[128 * 32];

  f32x4 acc[4][4] = {};

  const int row0 = t >> 2, cc = t & 3;
  const int wch = (t & 3) ^ ((t >> 3) & 3);  // write-side chunk swizzle
  const int fsw = (r >> 1) & 3;              // frag-read chunk swizzle

  f32x4 apre[2][2], bpre[2][2];

  auto prefetch = [&](int k0) {
#pragma unroll
    for (int i = 0; i < 2; ++i) {
      const float* pa = A + (size_t)(m0 + row0 + 64 * i) * DD + k0 + cc * 8;
      const float* pb = W + (size_t)(n0 + row0 + 64 * i) * DD + k0 + cc * 8;
      apre[i][0] = *(const f32x4*)pa;  apre[i][1] = *(const f32x4*)(pa + 4);
      bpre[i][0] = *(const f32x4*)pb;  bpre[i][1] = *(const f32x4*)(pb + 4);
    }
  };

  auto commit = [&]() {
#pragma unroll
    for (int i = 0; i < 2; ++i) {
      int row = row0 + 64 * i;
      f16x8 av, bv8;
#pragma unroll
      for (int j = 0; j < 4; ++j) {
        av[j]      = (_Float16)apre[i][0][j];
        av[4 + j]  = (_Float16)apre[i][1][j];
        bv8[j]     = (_Float16)bpre[i][0][j];
        bv8[4 + j] = (_Float16)bpre[i][1][j];
      }
      *(f16x8*)&sA[row * 32 + wch * 8] = av;
      *(f16x8*)&sB[row * 32 + wch * 8] = bv8;
    }
  };

  prefetch(0);

  for (int k0 = 0; k0 < DD; k0 += 32) {
    commit();
    __syncthreads();
    if (k0 + 32 < DD) prefetch(k0 + 32);

    f16x8 af[4], bf[4];
#pragma unroll
    for (int x = 0; x < 4; ++x) {
      af[x] = *(const f16x8*)&sA[(wm + x * 16 + r) * 32 + ((q ^ fsw) * 8)];
      bf[x] = *(const f16x8*)&sB[(wn + x * 16 + r) * 32 + ((q ^ fsw) * 8)];
    }
#pragma unroll
    for (int mi = 0; mi < 4; ++mi)
#pragma unroll
      for (int ni = 0; ni < 4; ++ni)
        acc[mi][ni] = __builtin_amdgcn_mfma_f32_16x16x32_f16(af[mi], bf[ni], acc[mi][ni], 0, 0, 0);
    __syncthreads();
  }

  // epilogue: C/D layout col=lane&15, row=(lane>>4)*4+reg
  if (z == 2) {
    // V^T + kappa permutation: [B,H,DK, (s&~63) + kappa(s&63)], kappa(k)=(k&15)*4+(k>>4)
#pragma unroll
    for (int ni = 0; ni < 4; ++ni) {
      int gn = n0 + wn + ni * 16 + r;
      float bv = bias[gn];
      int h = gn >> 6, dk = gn & 63;
#pragma unroll
      for (int mi = 0; mi < 4; ++mi) {
        int gm = m0 + wm + mi * 16 + q * 4;
        int bb = gm >> 11, s0 = gm & 2047;
        int kl = s0 & 63;                       // kl % 4 == 0
        int kap0 = (kl & 15) * 4 + (kl >> 4);   // kappa of s0; +rr -> kap0+rr*4
        size_t base = ((size_t)((bb * HH + h) * DKC + dk)) * SS + (s0 - kl);
#pragma unroll
        for (int rr = 0; rr < 4; ++rr)
          out[base + kap0 + rr * 4] = (_Float16)(acc[mi][ni][rr] + bv);
      }
    }
  } else {
#pragma unroll
    for (int ni = 0; ni < 4; ++ni) {
      int gn = n0 + wn + ni * 16 + r;
      float bv = bias[gn];
      int h = gn >> 6, dk = gn & 63;
#pragma unroll
      for (int mi = 0; mi < 4; ++mi) {
#pragma unroll
        for (int rr = 0; rr < 4; ++rr) {
          int gm = m0 + wm + mi * 16 + q * 4 + rr;
          int bb = gm >> 11, s = gm & 2047;
          out[((size_t)((bb * HH + h) * SS + s)) * DKC + dk] = (_Float16)(acc[mi][ni][rr] + bv);
        }
      }
    }
  }
}

// ---------------- flash attention: one (b,h,q-tile of 128) per block ----------------
// R10 (unchanged since): full-depth XOR swizzle on sVt and sP: bank conflicts
// 1.9e7 -> 0, 121 -> 105 us. P-store granule g=(r>>1)^(prow&7) keeps the
// packed b64 store conflict-free; reads use chunk^(r&7) like sK. sMB as f16
// (-30000 saturates exp2 to 0): LDS 36 KB.
__global__ __launch_bounds__(256) void attn(const _Float16* __restrict__ Pj,
                                            const int* __restrict__ mask,
                                            _Float16* __restrict__ Cx) {
  const int qt = blockIdx.x, h = blockIdx.y, bb = blockIdx.z;
  const size_t hoff = ((size_t)(bb * HH + h) * SS) * DKC;
  const _Float16* Qh  = Pj + hoff;
  const _Float16* Kh  = Pj + (size_t)MT * DD + hoff;
  const _Float16* Vth = Pj + (size_t)2 * MT * DD + hoff;  // [DK][tile*64+kappa]
  _Float16* Ch = Cx + hoff;
  const int* mrow = mask + bb * SS;

  const int t = threadIdx.x, lane = t & 63, wave = t >> 6;
  const int q = lane >> 4, r = lane & 15;
  const int qrow0 = qt * 128 + wave * 32;   // each wave owns 32 Q rows

  __shared__ __align__(16) _Float16 sK[64 * 64];      // [key][dk], chunk-xor swizzled
  __shared__ __align__(16) _Float16 sVt[64 * 64];     // [dk][kappa], chunk-xor swizzled
  __shared__ __align__(16) _Float16 sP[4][32 * 64];   // per-wave P [qrow][kappa], chunk-xor swizzled
  __shared__ __align__(16) _Float16 sMBh[SS];         // mask bias (0 / -30000), 4 KB

  // stage mask bias once: 2048 entries / 256 threads = 8 each
  {
    int i0 = t * 8;
    i32x4 m0v = *(const i32x4*)(mrow + i0);
    i32x4 m1v = *(const i32x4*)(mrow + i0 + 4);
    f16x8 bvv;
#pragma unroll
    for (int j = 0; j < 4; ++j) {
      bvv[j]     = m0v[j] ? (_Float16)0.0f : (_Float16)(-30000.0f);
      bvv[4 + j] = m1v[j] ? (_Float16)0.0f : (_Float16)(-30000.0f);
    }
    *(f16x8*)&sMBh[i0] = bvv;
  }

  // Q in registers as A-fragments: A[m=lane&15][k=quad*8+j]
  f16x8 qf[2][2];
#pragma unroll
  for (int mi = 0; mi < 2; ++mi)
#pragma unroll
    for (int kk = 0; kk < 2; ++kk)
      qf[mi][kk] = *(const f16x8*)&Qh[(size_t)(qrow0 + mi * 16 + r) * DKC + kk * 32 + q * 8];

  float lst[2][4] = {};           // lane-local partial row sums
  f32x4 oacc[2][4] = {};

  const float C2 = 0.125f * 1.44269504089f;  // log2(e)/sqrt(DK)

  // staging coords: 256 thr x 2 iters = 64 rows x 8 chunks of 16 B
  const int srow0 = t >> 3, scc = t & 7;

  // prefetch tile 0 into registers
  f16x8 kpre[2], vpre[2];
#pragma unroll
  for (int i = 0; i < 2; ++i) {
    int row = srow0 + 32 * i;
    kpre[i] = *(const f16x8*)(Kh + (size_t)row * DKC + scc * 8);
    vpre[i] = *(const f16x8*)(Vth + (size_t)row * SS + scc * 8);
  }

  for (int kt = 0; kt < SS; kt += 64) {
    // commit prefetched tile to LDS (full (row&7) granule xor on both arrays)
#pragma unroll
    for (int i = 0; i < 2; ++i) {
      int row = srow0 + 32 * i;
      *(f16x8*)&sK [row * 64 + ((scc ^ (row & 7)) << 3)] = kpre[i];
      *(f16x8*)&sVt[row * 64 + ((scc ^ (row & 7)) << 3)] = vpre[i];
    }
    __syncthreads();   // also covers sMBh visibility on first iteration

    // issue next tile's global loads now; vmcnt drains at the NEXT commit
    if (kt + 64 < SS) {
#pragma unroll
      for (int i = 0; i < 2; ++i) {
        int row = srow0 + 32 * i;
        kpre[i] = *(const f16x8*)(Kh + (size_t)(kt + 64 + row) * DKC + scc * 8);
        vpre[i] = *(const f16x8*)(Vth + (size_t)row * SS + kt + 64 + scc * 8);
      }
    }

    // scores = Q @ K^T
    f32x4 sacc[2][4] = {};
#pragma unroll
    for (int kk = 0; kk < 2; ++kk) {
      f16x8 kb[4];
#pragma unroll
      for (int ni = 0; ni < 4; ++ni)
        kb[ni] = *(const f16x8*)&sK[(ni * 16 + r) * 64 + (((kk * 4 + q) ^ (r & 7)) << 3)];
      __builtin_amdgcn_s_setprio(1);
#pragma unroll
      for (int mi = 0; mi < 2; ++mi)
#pragma unroll
        for (int ni = 0; ni < 4; ++ni)
          sacc[mi][ni] = __builtin_amdgcn_mfma_f32_16x16x32_f16(qf[mi][kk], kb[ni], sacc[mi][ni], 0, 0, 0);
      __builtin_amdgcn_s_setprio(0);
    }

    float mb[4];
#pragma unroll
    for (int ni = 0; ni < 4; ++ni) mb[ni] = (float)sMBh[kt + ni * 16 + r];  // LDS, lgkmcnt only

    // p = exp2(s*C2 + maskbias); packed store: kappa(key=ni*16+r) = r*4+ni ->
    // 4 contiguous f16 at granule (r>>1) of row prow, placed at g=(r>>1)^(prow&7)
#pragma unroll
    for (int mi = 0; mi < 2; ++mi) {
#pragma unroll
      for (int rr = 0; rr < 4; ++rr) {
        float pp[4];
#pragma unroll
        for (int ni = 0; ni < 4; ++ni)
          pp[ni] = __builtin_amdgcn_exp2f(__builtin_fmaf(sacc[mi][ni][rr], C2, mb[ni]));
        lst[mi][rr] += (pp[0] + pp[1]) + (pp[2] + pp[3]);
        int prow = mi * 16 + q * 4 + rr;
        int g = (r >> 1) ^ ((q * 4 + rr) & 7);       // (r>>1) ^ (prow&7)
        int goff = prow * 64 + (g << 3) + ((r & 1) << 2);
        unsigned lo = __builtin_bit_cast(unsigned, __builtin_amdgcn_cvt_pkrtz(pp[0], pp[1]));
        unsigned hi = __builtin_bit_cast(unsigned, __builtin_amdgcn_cvt_pkrtz(pp[2], pp[3]));
        uint2 u; u.x = lo; u.y = hi;
        *(uint2*)&sP[wave][goff] = u;
      }
    }
    __threadfence_block();  // wave-local LDS write->read ordering

    // O += P @ V   (contraction over kappa; P cols and V rows share the permutation)
#pragma unroll
    for (int kk = 0; kk < 2; ++kk) {
      f16x8 ap[2], vb[4];
#pragma unroll
      for (int mi = 0; mi < 2; ++mi)
        ap[mi] = *(const f16x8*)&sP[wave][(mi * 16 + r) * 64 + (((kk * 4 + q) ^ (r & 7)) << 3)];
#pragma unroll
      for (int ni = 0; ni < 4; ++ni)
        vb[ni] = *(const f16x8*)&sVt[(ni * 16 + r) * 64 + (((kk * 4 + q) ^ (r & 7)) << 3)];
      __builtin_amdgcn_s_setprio(1);
#pragma unroll
      for (int mi = 0; mi < 2; ++mi)
#pragma unroll
        for (int ni = 0; ni < 4; ++ni)
          oacc[mi][ni] = __builtin_amdgcn_mfma_f32_16x16x32_f16(ap[mi], vb[ni], oacc[mi][ni], 0, 0, 0);
      __builtin_amdgcn_s_setprio(0);
    }
    __syncthreads();
  }

  // epilogue: reduce row sums across the 16-lane r-groups, normalize, store
#pragma unroll
  for (int mi = 0; mi < 2; ++mi)
#pragma unroll
    for (int rr = 0; rr < 4; ++rr) {
      float l = lst[mi][rr];
#pragma unroll
      for (int d = 1; d < 16; d <<= 1) l += __shfl_xor(l, d);
      lst[mi][rr] = 1.0f / l;
    }

#pragma unroll
  for (int mi = 0; mi < 2; ++mi)
#pragma unroll
    for (int ni = 0; ni < 4; ++ni)
#pragma unroll
      for (int rr = 0; rr < 4; ++rr) {
        int row = qrow0 + mi * 16 + q * 4 + rr;
        Ch[(size_t)row * DKC + ni * 16 + r] = (_Float16)(oacc[mi][ni][rr] * lst[mi][rr]);
      }
}

// ---------------- output projection: out = ctx @ Wo^T + bo (fp32 out) ----------------
// R12: same single-buffer reg-staged structure; A (ctx) is f16 from attn,
// B (Wo) read as fp32 and converted in the commit.
__global__ __launch_bounds__(256) void gemm_out(const _Float16* __restrict__ Cx,
                                                const float* __restrict__ W,
                                                const float* __restrict__ bias,
                                                float* __restrict__ out) {
  const int m0 = blockIdx.x * 128;
  const int n0 = blockIdx.y * 128;
  const int t = threadIdx.x;
  const int lane = t & 63;
  const int wave = t >> 6;
  const int q = lane >> 4, r = lane & 15;
  const int wm = (wave & 1) * 64, wn = (wave >> 1) * 64;

  __shared__ __align__(16) _Float16 sA[128 * 32];
  __shared__ __align__(16) _Float16 sB[128 * 32];

  f32x4 acc[4][4] = {};

  const int row0 = t >> 2, cc = t & 3;
  const int wch = (t & 3) ^ ((t >> 3) & 3);
  const int fsw = (r >> 1) & 3;

  size_t abase[2];
#pragma unroll
  for (int i = 0; i < 2; ++i) {
    int gm = m0 + row0 + 64 * i;
    int bb = gm >> 11, s = gm & 2047;
    abase[i] = ((size_t)(bb * HH) * SS + s) * DKC;
  }

  f16x8 apre[2];
  f32x4 bpre[2][2];

  auto prefetch = [&](int k0) {
    int head = k0 >> 6, off = (k0 & 63) + cc * 8;
#pragma unroll
    for (int i = 0; i < 2; ++i) {
      apre[i] = *(const f16x8*)(Cx + abase[i] + (size_t)head * SS * DKC + off);
      const float* pb = W + (size_t)(n0 + row0 + 64 * i) * DD + k0 + cc * 8;
      bpre[i][0] = *(const f32x4*)pb;  bpre[i][1] = *(const f32x4*)(pb + 4);
    }
  };

  auto commit = [&]() {
#pragma unroll
    for (int i = 0; i < 2; ++i) {
      int row = row0 + 64 * i;
      f16x8 bv8;
#pragma unroll
      for (int j = 0; j < 4; ++j) {
        bv8[j]     = (_Float16)bpre[i][0][j];
        bv8[4 + j] = (_Float16)bpre[i][1][j];
      }
      *(f16x8*)&sA[row * 32 + wch * 8] = apre[i];
      *(f16x8*)&sB[row * 32 + wch * 8] = bv8;
    }
  };

  prefetch(0);

  for (int k0 = 0; k0 < DD; k0 += 32) {
    commit();
    __syncthreads();
    if (k0 + 32 < DD) prefetch(k0 + 32);

    f16x8 af[4], bf[4];
#pragma unroll
    for (int x = 0; x < 4; ++x) {
      af[x] = *(const f16x8*)&sA[(wm + x * 16 + r) * 32 + ((q ^ fsw) * 8)];
      bf[x] = *(const f16x8*)&sB[(wn + x * 16 + r) * 32 + ((q ^ fsw) * 8)];
    }
#pragma unroll
    for (int mi = 0; mi < 4; ++mi)
#pragma unroll
      for (int ni = 0; ni < 4; ++ni)
        acc[mi][ni] = __builtin_amdgcn_mfma_f32_16x16x32_f16(af[mi], bf[ni], acc[mi][ni], 0, 0, 0);
    __syncthreads();
  }

#pragma unroll
  for (int ni = 0; ni < 4; ++ni) {
    int gn = n0 + wn + ni * 16 + r;
    float bv = bias[gn];
#pragma unroll
    for (int mi = 0; mi < 4; ++mi) {
#pragma unroll
      for (int rr = 0; rr < 4; ++rr) {
        int gm = m0 + wm + mi * 16 + q * 4 + rr;
        out[(size_t)gm * DD + gn] = acc[mi][ni][rr] + bv;
      }
    }
  }
}

extern "C" void kernel_launch(void* const* d_in, const int* in_sizes, int n_in,
                              void* d_out, int out_size, void* d_ws, size_t ws_size,
                              hipStream_t stream) {
  const float* query = (const float*)d_in[0];
  const float* key_  = (const float*)d_in[1];
  const float* value = (const float*)d_in[2];
  const int*   mask  = (const int*)d_in[3];
  const float* Wq = (const float*)d_in[4];
  const float* bq = (const float*)d_in[5];
  const float* Wk = (const float*)d_in[6];
  const float* bk = (const float*)d_in[7];
  const float* Wv = (const float*)d_in[8];
  const float* bv = (const float*)d_in[9];
  const float* Wo = (const float*)d_in[10];
  const float* bo = (const float*)d_in[11];
  float* out = (float*)d_out;

  // workspace layout (fp16): proj Q,K [B,H,S,DK] + Vpi [B,H,DK,S'] | ctx
  _Float16* Pj = (_Float16*)d_ws;
  _Float16* Cx = Pj + (size_t)3 * NX;

  gemm_qkv<<<dim3(MT / 128, DD / 128, 3), 256, 0, stream>>>(query, key_, value, Wq, Wk, Wv,
                                                            bq, bk, bv, Pj);
  attn<<<dim3(SS / 128, HH, BB), 256, 0, stream>>>(Pj, mask, Cx);
  gemm_out<<<dim3(MT / 128, DD / 128), 256, 0, stream>>>(Cx, Wo, bo, out);
}

// Round 4
// 385.600 us; speedup vs baseline: 1.0358x; 1.0358x over previous
//
#include <hip/hip_runtime.h>

#define BB 4
#define SS 2048
#define DD 1024
#define HH 16
#define DKC 64
#define MT (BB*SS)   // 8192 rows total
#define NX (MT*DD)   // 8388608
#define NW (DD*DD)   // 1048576

typedef _Float16 f16x8 __attribute__((ext_vector_type(8)));
typedef _Float16 f16x4 __attribute__((ext_vector_type(4)));
typedef float f32x4 __attribute__((ext_vector_type(4)));
typedef int   i32x4 __attribute__((ext_vector_type(4)));

// ---------------- fp32 -> fp16 conversion, one flat kernel over X(q,k,v)|W(q,k,v,o) ----------------
// Restored from R0/R1: f16 GEMM inputs beat fused-fp32 reads by ~40+ us
// (R3 measured: fp32 prefetch doubles bytes+latency chain and blows L2 footprint).
__global__ __launch_bounds__(256) void cvt_all(const float* __restrict__ xq,
                                               const float* __restrict__ xk,
                                               const float* __restrict__ xv,
                                               const float* __restrict__ wq,
                                               const float* __restrict__ wk,
                                               const float* __restrict__ wv,
                                               const float* __restrict__ wo,
                                               _Float16* __restrict__ dst) {
  size_t i = ((size_t)blockIdx.x * 256 + threadIdx.x) * 4;
  const float* src; size_t off;
  if (i < (size_t)NX)          { src = xq; off = i; }
  else if (i < (size_t)2*NX)   { src = xk; off = i - (size_t)NX; }
  else if (i < (size_t)3*NX)   { src = xv; off = i - (size_t)2*NX; }
  else {
    size_t j = i - (size_t)3*NX;
    if (j < (size_t)NW)        { src = wq; off = j; }
    else if (j < (size_t)2*NW) { src = wk; off = j - (size_t)NW; }
    else if (j < (size_t)3*NW) { src = wv; off = j - (size_t)2*NW; }
    else                       { src = wo; off = j - (size_t)3*NW; }
  }
  f32x4 f = *(const f32x4*)(src + off);
  f16x4 o;
#pragma unroll
  for (int j = 0; j < 4; ++j) o[j] = (_Float16)f[j];
  *(f16x4*)(dst + i) = o;
}

// ---------------- QKV projection: Y = X @ W^T + b ----------------
// R13: occupancy-first. Evidence R0..R3: non-attn time is monotone in
// LDS/block (250/259/271 us at 16/32/48 KB) and fp32 loads are the worst
// (293). These K=1024 GEMMs are latency/TLP-bound (R3 PMC: MfmaUtil 14.6,
// VALUBusy 12, HBM 13.7, Occ 22 -- every pipe idle). So: reg-staged f16
// single-buffer (R0's best structure) + conflict-free chunk swizzle
// (validated R3) + BM=64 tile: grid 1536->3072 blocks (12/CU queued),
// LDS 12 KB, acc[2][4] (32 VGPR) -> more resident waves per CU.
__global__ __launch_bounds__(256) void gemm_qkv(const _Float16* __restrict__ Xb,
                                                const _Float16* __restrict__ Wb,
                                                const float* __restrict__ b0,
                                                const float* __restrict__ b1,
                                                const float* __restrict__ b2,
                                                _Float16* __restrict__ Pj) {
  const int z = blockIdx.z;
  const _Float16* A = Xb + (size_t)z * MT * DD;
  const _Float16* W = Wb + (size_t)z * DD * DD;
  const float* bias = (z == 0) ? b0 : ((z == 1) ? b1 : b2);
  _Float16* out = Pj + (size_t)z * MT * DD;

  const int m0 = blockIdx.x * 64;    // m fastest -> consecutive blocks share B panel
  const int n0 = blockIdx.y * 128;
  const int t = threadIdx.x;
  const int lane = t & 63;
  const int wave = t >> 6;
  const int q = lane >> 4, r = lane & 15;
  const int wm = (wave & 1) * 32, wn = (wave >> 1) * 64;  // 2x2 waves over 64x128

  __shared__ __align__(16) _Float16 sA[64 * 32];
  __shared__ __align__(16) _Float16 sB[128 * 32];

  f32x4 acc[2][4] = {};

  const int row0 = t >> 2, cc = t & 3;
  const int wch = (t & 3) ^ ((t >> 3) & 3);  // write-side chunk swizzle (= cc ^ (row>>1)&3)
  const int fsw = (r >> 1) & 3;              // frag-read chunk swizzle

  f16x8 apre, bpre[2];

  auto prefetch = [&](int k0) {
    apre = *(const f16x8*)(A + (size_t)(m0 + row0) * DD + k0 + cc * 8);
#pragma unroll
    for (int i = 0; i < 2; ++i)
      bpre[i] = *(const f16x8*)(W + (size_t)(n0 + row0 + 64 * i) * DD + k0 + cc * 8);
  };

  auto commit = [&]() {
    *(f16x8*)&sA[row0 * 32 + wch * 8] = apre;
#pragma unroll
    for (int i = 0; i < 2; ++i)
      *(f16x8*)&sB[(row0 + 64 * i) * 32 + wch * 8] = bpre[i];
  };

  prefetch(0);

  for (int k0 = 0; k0 < DD; k0 += 32) {
    commit();
    __syncthreads();
    if (k0 + 32 < DD) prefetch(k0 + 32);

    f16x8 af[2], bf[4];
#pragma unroll
    for (int mi = 0; mi < 2; ++mi)
      af[mi] = *(const f16x8*)&sA[(wm + mi * 16 + r) * 32 + ((q ^ fsw) * 8)];
#pragma unroll
    for (int ni = 0; ni < 4; ++ni)
      bf[ni] = *(const f16x8*)&sB[(wn + ni * 16 + r) * 32 + ((q ^ fsw) * 8)];
#pragma unroll
    for (int mi = 0; mi < 2; ++mi)
#pragma unroll
      for (int ni = 0; ni < 4; ++ni)
        acc[mi][ni] = __builtin_amdgcn_mfma_f32_16x16x32_f16(af[mi], bf[ni], acc[mi][ni], 0, 0, 0);
    __syncthreads();
  }

  // epilogue: C/D layout col=lane&15, row=(lane>>4)*4+reg
  if (z == 2) {
    // V^T + kappa permutation: [B,H,DK, (s&~63) + kappa(s&63)], kappa(k)=(k&15)*4+(k>>4)
#pragma unroll
    for (int ni = 0; ni < 4; ++ni) {
      int gn = n0 + wn + ni * 16 + r;
      float bv = bias[gn];
      int h = gn >> 6, dk = gn & 63;
#pragma unroll
      for (int mi = 0; mi < 2; ++mi) {
        int gm = m0 + wm + mi * 16 + q * 4;
        int bb = gm >> 11, s0 = gm & 2047;
        int kl = s0 & 63;                       // kl % 4 == 0
        int kap0 = (kl & 15) * 4 + (kl >> 4);   // kappa of s0; +rr -> kap0+rr*4
        size_t base = ((size_t)((bb * HH + h) * DKC + dk)) * SS + (s0 - kl);
#pragma unroll
        for (int rr = 0; rr < 4; ++rr)
          out[base + kap0 + rr * 4] = (_Float16)(acc[mi][ni][rr] + bv);
      }
    }
  } else {
#pragma unroll
    for (int ni = 0; ni < 4; ++ni) {
      int gn = n0 + wn + ni * 16 + r;
      float bv = bias[gn];
      int h = gn >> 6, dk = gn & 63;
#pragma unroll
      for (int mi = 0; mi < 2; ++mi) {
#pragma unroll
        for (int rr = 0; rr < 4; ++rr) {
          int gm = m0 + wm + mi * 16 + q * 4 + rr;
          int bb = gm >> 11, s = gm & 2047;
          out[((size_t)((bb * HH + h) * SS + s)) * DKC + dk] = (_Float16)(acc[mi][ni][rr] + bv);
        }
      }
    }
  }
}

// ---------------- flash attention: one (b,h,q-tile of 128) per block ----------------
// Unchanged since R10 (control): full-depth XOR swizzle on sVt/sP -> bank
// conflicts 0, 106 us. P-store granule g=(r>>1)^(prow&7); reads chunk^(r&7).
// sMB as f16 (-30000 saturates exp2 to 0): LDS 36 KB.
__global__ __launch_bounds__(256) void attn(const _Float16* __restrict__ Pj,
                                            const int* __restrict__ mask,
                                            _Float16* __restrict__ Cx) {
  const int qt = blockIdx.x, h = blockIdx.y, bb = blockIdx.z;
  const size_t hoff = ((size_t)(bb * HH + h) * SS) * DKC;
  const _Float16* Qh  = Pj + hoff;
  const _Float16* Kh  = Pj + (size_t)MT * DD + hoff;
  const _Float16* Vth = Pj + (size_t)2 * MT * DD + hoff;  // [DK][tile*64+kappa]
  _Float16* Ch = Cx + hoff;
  const int* mrow = mask + bb * SS;

  const int t = threadIdx.x, lane = t & 63, wave = t >> 6;
  const int q = lane >> 4, r = lane & 15;
  const int qrow0 = qt * 128 + wave * 32;   // each wave owns 32 Q rows

  __shared__ __align__(16) _Float16 sK[64 * 64];      // [key][dk], chunk-xor swizzled
  __shared__ __align__(16) _Float16 sVt[64 * 64];     // [dk][kappa], chunk-xor swizzled
  __shared__ __align__(16) _Float16 sP[4][32 * 64];   // per-wave P [qrow][kappa], chunk-xor swizzled
  __shared__ __align__(16) _Float16 sMBh[SS];         // mask bias (0 / -30000), 4 KB

  // stage mask bias once: 2048 entries / 256 threads = 8 each
  {
    int i0 = t * 8;
    i32x4 m0v = *(const i32x4*)(mrow + i0);
    i32x4 m1v = *(const i32x4*)(mrow + i0 + 4);
    f16x8 bvv;
#pragma unroll
    for (int j = 0; j < 4; ++j) {
      bvv[j]     = m0v[j] ? (_Float16)0.0f : (_Float16)(-30000.0f);
      bvv[4 + j] = m1v[j] ? (_Float16)0.0f : (_Float16)(-30000.0f);
    }
    *(f16x8*)&sMBh[i0] = bvv;
  }

  // Q in registers as A-fragments: A[m=lane&15][k=quad*8+j]
  f16x8 qf[2][2];
#pragma unroll
  for (int mi = 0; mi < 2; ++mi)
#pragma unroll
    for (int kk = 0; kk < 2; ++kk)
      qf[mi][kk] = *(const f16x8*)&Qh[(size_t)(qrow0 + mi * 16 + r) * DKC + kk * 32 + q * 8];

  float lst[2][4] = {};           // lane-local partial row sums
  f32x4 oacc[2][4] = {};

  const float C2 = 0.125f * 1.44269504089f;  // log2(e)/sqrt(DK)

  // staging coords: 256 thr x 2 iters = 64 rows x 8 chunks of 16 B
  const int srow0 = t >> 3, scc = t & 7;

  // prefetch tile 0 into registers
  f16x8 kpre[2], vpre[2];
#pragma unroll
  for (int i = 0; i < 2; ++i) {
    int row = srow0 + 32 * i;
    kpre[i] = *(const f16x8*)(Kh + (size_t)row * DKC + scc * 8);
    vpre[i] = *(const f16x8*)(Vth + (size_t)row * SS + scc * 8);
  }

  for (int kt = 0; kt < SS; kt += 64) {
    // commit prefetched tile to LDS (full (row&7) granule xor on both arrays)
#pragma unroll
    for (int i = 0; i < 2; ++i) {
      int row = srow0 + 32 * i;
      *(f16x8*)&sK [row * 64 + ((scc ^ (row & 7)) << 3)] = kpre[i];
      *(f16x8*)&sVt[row * 64 + ((scc ^ (row & 7)) << 3)] = vpre[i];
    }
    __syncthreads();   // also covers sMBh visibility on first iteration

    // issue next tile's global loads now; vmcnt drains at the NEXT commit
    if (kt + 64 < SS) {
#pragma unroll
      for (int i = 0; i < 2; ++i) {
        int row = srow0 + 32 * i;
        kpre[i] = *(const f16x8*)(Kh + (size_t)(kt + 64 + row) * DKC + scc * 8);
        vpre[i] = *(const f16x8*)(Vth + (size_t)row * SS + kt + 64 + scc * 8);
      }
    }

    // scores = Q @ K^T
    f32x4 sacc[2][4] = {};
#pragma unroll
    for (int kk = 0; kk < 2; ++kk) {
      f16x8 kb[4];
#pragma unroll
      for (int ni = 0; ni < 4; ++ni)
        kb[ni] = *(const f16x8*)&sK[(ni * 16 + r) * 64 + (((kk * 4 + q) ^ (r & 7)) << 3)];
      __builtin_amdgcn_s_setprio(1);
#pragma unroll
      for (int mi = 0; mi < 2; ++mi)
#pragma unroll
        for (int ni = 0; ni < 4; ++ni)
          sacc[mi][ni] = __builtin_amdgcn_mfma_f32_16x16x32_f16(qf[mi][kk], kb[ni], sacc[mi][ni], 0, 0, 0);
      __builtin_amdgcn_s_setprio(0);
    }

    float mb[4];
#pragma unroll
    for (int ni = 0; ni < 4; ++ni) mb[ni] = (float)sMBh[kt + ni * 16 + r];  // LDS, lgkmcnt only

    // p = exp2(s*C2 + maskbias); packed store: kappa(key=ni*16+r) = r*4+ni ->
    // 4 contiguous f16 at granule (r>>1) of row prow, placed at g=(r>>1)^(prow&7)
#pragma unroll
    for (int mi = 0; mi < 2; ++mi) {
#pragma unroll
      for (int rr = 0; rr < 4; ++rr) {
        float pp[4];
#pragma unroll
        for (int ni = 0; ni < 4; ++ni)
          pp[ni] = __builtin_amdgcn_exp2f(__builtin_fmaf(sacc[mi][ni][rr], C2, mb[ni]));
        lst[mi][rr] += (pp[0] + pp[1]) + (pp[2] + pp[3]);
        int prow = mi * 16 + q * 4 + rr;
        int g = (r >> 1) ^ ((q * 4 + rr) & 7);       // (r>>1) ^ (prow&7)
        int goff = prow * 64 + (g << 3) + ((r & 1) << 2);
        unsigned lo = __builtin_bit_cast(unsigned, __builtin_amdgcn_cvt_pkrtz(pp[0], pp[1]));
        unsigned hi = __builtin_bit_cast(unsigned, __builtin_amdgcn_cvt_pkrtz(pp[2], pp[3]));
        uint2 u; u.x = lo; u.y = hi;
        *(uint2*)&sP[wave][goff] = u;
      }
    }
    __threadfence_block();  // wave-local LDS write->read ordering

    // O += P @ V   (contraction over kappa; P cols and V rows share the permutation)
#pragma unroll
    for (int kk = 0; kk < 2; ++kk) {
      f16x8 ap[2], vb[4];
#pragma unroll
      for (int mi = 0; mi < 2; ++mi)
        ap[mi] = *(const f16x8*)&sP[wave][(mi * 16 + r) * 64 + (((kk * 4 + q) ^ (r & 7)) << 3)];
#pragma unroll
      for (int ni = 0; ni < 4; ++ni)
        vb[ni] = *(const f16x8*)&sVt[(ni * 16 + r) * 64 + (((kk * 4 + q) ^ (r & 7)) << 3)];
      __builtin_amdgcn_s_setprio(1);
#pragma unroll
      for (int mi = 0; mi < 2; ++mi)
#pragma unroll
        for (int ni = 0; ni < 4; ++ni)
          oacc[mi][ni] = __builtin_amdgcn_mfma_f32_16x16x32_f16(ap[mi], vb[ni], oacc[mi][ni], 0, 0, 0);
      __builtin_amdgcn_s_setprio(0);
    }
    __syncthreads();
  }

  // epilogue: reduce row sums across the 16-lane r-groups, normalize, store
#pragma unroll
  for (int mi = 0; mi < 2; ++mi)
#pragma unroll
    for (int rr = 0; rr < 4; ++rr) {
      float l = lst[mi][rr];
#pragma unroll
      for (int d = 1; d < 16; d <<= 1) l += __shfl_xor(l, d);
      lst[mi][rr] = 1.0f / l;
    }

#pragma unroll
  for (int mi = 0; mi < 2; ++mi)
#pragma unroll
    for (int ni = 0; ni < 4; ++ni)
#pragma unroll
      for (int rr = 0; rr < 4; ++rr) {
        int row = qrow0 + mi * 16 + q * 4 + rr;
        Ch[(size_t)row * DKC + ni * 16 + r] = (_Float16)(oacc[mi][ni][rr] * lst[mi][rr]);
      }
}

// ---------------- output projection: out = ctx @ Wo^T + bo (fp32 out) ----------------
// R13: BM=64 tile -> grid 512->1024 blocks (was 2 blocks/CU, the most
// block-starved kernel at ~130 us / 130 TF in R3). Same reg-staged f16
// single-buffer structure as gemm_qkv.
__global__ __launch_bounds__(256) void gemm_out(const _Float16* __restrict__ Cx,
                                                const _Float16* __restrict__ W,
                                                const float* __restrict__ bias,
                                                float* __restrict__ out) {
  const int m0 = blockIdx.x * 64;
  const int n0 = blockIdx.y * 128;
  const int t = threadIdx.x;
  const int lane = t & 63;
  const int wave = t >> 6;
  const int q = lane >> 4, r = lane & 15;
  const int wm = (wave & 1) * 32, wn = (wave >> 1) * 64;

  __shared__ __align__(16) _Float16 sA[64 * 32];
  __shared__ __align__(16) _Float16 sB[128 * 32];

  f32x4 acc[2][4] = {};

  const int row0 = t >> 2, cc = t & 3;
  const int wch = (t & 3) ^ ((t >> 3) & 3);
  const int fsw = (r >> 1) & 3;

  size_t abase;
  {
    int gm = m0 + row0;
    int bb = gm >> 11, s = gm & 2047;
    abase = ((size_t)(bb * HH) * SS + s) * DKC;
  }

  f16x8 apre, bpre[2];

  auto prefetch = [&](int k0) {
    int head = k0 >> 6, off = (k0 & 63) + cc * 8;
    apre = *(const f16x8*)(Cx + abase + (size_t)head * SS * DKC + off);
#pragma unroll
    for (int i = 0; i < 2; ++i)
      bpre[i] = *(const f16x8*)(W + (size_t)(n0 + row0 + 64 * i) * DD + k0 + cc * 8);
  };

  auto commit = [&]() {
    *(f16x8*)&sA[row0 * 32 + wch * 8] = apre;
#pragma unroll
    for (int i = 0; i < 2; ++i)
      *(f16x8*)&sB[(row0 + 64 * i) * 32 + wch * 8] = bpre[i];
  };

  prefetch(0);

  for (int k0 = 0; k0 < DD; k0 += 32) {
    commit();
    __syncthreads();
    if (k0 + 32 < DD) prefetch(k0 + 32);

    f16x8 af[2], bf[4];
#pragma unroll
    for (int mi = 0; mi < 2; ++mi)
      af[mi] = *(const f16x8*)&sA[(wm + mi * 16 + r) * 32 + ((q ^ fsw) * 8)];
#pragma unroll
    for (int ni = 0; ni < 4; ++ni)
      bf[ni] = *(const f16x8*)&sB[(wn + ni * 16 + r) * 32 + ((q ^ fsw) * 8)];
#pragma unroll
    for (int mi = 0; mi < 2; ++mi)
#pragma unroll
      for (int ni = 0; ni < 4; ++ni)
        acc[mi][ni] = __builtin_amdgcn_mfma_f32_16x16x32_f16(af[mi], bf[ni], acc[mi][ni], 0, 0, 0);
    __syncthreads();
  }

#pragma unroll
  for (int ni = 0; ni < 4; ++ni) {
    int gn = n0 + wn + ni * 16 + r;
    float bv = bias[gn];
#pragma unroll
    for (int mi = 0; mi < 2; ++mi) {
#pragma unroll
      for (int rr = 0; rr < 4; ++rr) {
        int gm = m0 + wm + mi * 16 + q * 4 + rr;
        out[(size_t)gm * DD + gn] = acc[mi][ni][rr] + bv;
      }
    }
  }
}

extern "C" void kernel_launch(void* const* d_in, const int* in_sizes, int n_in,
                              void* d_out, int out_size, void* d_ws, size_t ws_size,
                              hipStream_t stream) {
  const float* query = (const float*)d_in[0];
  const float* key_  = (const float*)d_in[1];
  const float* value = (const float*)d_in[2];
  const int*   mask  = (const int*)d_in[3];
  const float* Wq = (const float*)d_in[4];
  const float* bq = (const float*)d_in[5];
  const float* Wk = (const float*)d_in[6];
  const float* bk = (const float*)d_in[7];
  const float* Wv = (const float*)d_in[8];
  const float* bv = (const float*)d_in[9];
  const float* Wo = (const float*)d_in[10];
  const float* bo = (const float*)d_in[11];
  float* out = (float*)d_out;

  // workspace layout (fp16): X(q,k,v) | W(q,k,v,o) | proj Q,K [B,H,S,DK] + Vpi [B,H,DK,S'] | ctx
  _Float16* Xb = (_Float16*)d_ws;
  _Float16* Wb = Xb + (size_t)3 * NX;
  _Float16* Pj = Wb + (size_t)4 * NW;
  _Float16* Cx = Pj + (size_t)3 * NX;

  cvt_all<<<(3 * NX + 4 * NW) / 1024, 256, 0, stream>>>(query, key_, value, Wq, Wk, Wv, Wo, Xb);

  gemm_qkv<<<dim3(MT / 64, DD / 128, 3), 256, 0, stream>>>(Xb, Wb, bq, bk, bv, Pj);
  attn<<<dim3(SS / 128, HH, BB), 256, 0, stream>>>(Pj, mask, Cx);
  gemm_out<<<dim3(MT / 64, DD / 128), 256, 0, stream>>>(Cx, Wb + (size_t)3 * NW, bo, out);
}

// Round 5
// 346.713 us; speedup vs baseline: 1.1520x; 1.1122x over previous
//
#include <hip/hip_runtime.h>

#define BB 4
#define SS 2048
#define DD 1024
#define HH 16
#define DKC 64
#define MT (BB*SS)   // 8192 rows total
#define NX (MT*DD)   // 8388608
#define NW (DD*DD)   // 1048576

typedef _Float16 f16x8 __attribute__((ext_vector_type(8)));
typedef _Float16 f16x4 __attribute__((ext_vector_type(4)));
typedef float f32x4 __attribute__((ext_vector_type(4)));
typedef int   i32x4 __attribute__((ext_vector_type(4)));
typedef unsigned u32x4 __attribute__((ext_vector_type(4)));

// ---------------- fp32 -> fp16 conversion (R1-proven; f16 GEMM inputs beat fused fp32 by >40us) ----
__global__ __launch_bounds__(256) void cvt_all(const float* __restrict__ xq,
                                               const float* __restrict__ xk,
                                               const float* __restrict__ xv,
                                               const float* __restrict__ wq,
                                               const float* __restrict__ wk,
                                               const float* __restrict__ wv,
                                               const float* __restrict__ wo,
                                               _Float16* __restrict__ dst) {
  size_t i = ((size_t)blockIdx.x * 256 + threadIdx.x) * 4;
  const float* src; size_t off;
  if (i < (size_t)NX)          { src = xq; off = i; }
  else if (i < (size_t)2*NX)   { src = xk; off = i - (size_t)NX; }
  else if (i < (size_t)3*NX)   { src = xv; off = i - (size_t)2*NX; }
  else {
    size_t j = i - (size_t)3*NX;
    if (j < (size_t)NW)        { src = wq; off = j; }
    else if (j < (size_t)2*NW) { src = wk; off = j - (size_t)NW; }
    else if (j < (size_t)3*NW) { src = wv; off = j - (size_t)2*NW; }
    else                       { src = wo; off = j - (size_t)3*NW; }
  }
  f32x4 f = *(const f32x4*)(src + off);
  f16x4 o;
#pragma unroll
  for (int j = 0; j < 4; ++j) o[j] = (_Float16)f[j];
  *(f16x4*)(dst + i) = o;
}

// ---------------- QKV projection: Y = X @ W^T + b ----------------
// R14: main loop = EXACT R0 structure (reg-staged f16, single buffer, BM=128,
// 16 KB LDS -> best of 5 measured variants) + conflict-free chunk swizzle
// (refcheck-validated R3/R4, conflicts=0).
// Epilogues reworked for packed b64 stores:
//  - Q,K (z<2): stored with dk-permutation sigma(dk)=(dk&15)*4+(dk>>4) applied
//    IDENTICALLY to Q and K -> QK^T invariant (contraction is position-based in
//    attn). 4 ni-values land contiguous -> 16 coalesced b64 stores (was 64 b16).
//  - V (z==2): [B,H,DK, tile(s)*64 + kappa(s&63)] with kappa(key) =
//    (key&3) + 4*((key>>4)&1) + 8*((key>>2)&3) + 32*(key>>5)  (bit shuffle).
//    Chosen so attn's swapped-QK P-fragments are PV A-operands IN REGISTERS.
//    kappa(kl+rr)=kappa0+rr -> still a contiguous b64 store per (mi,ni).
__global__ __launch_bounds__(256) void gemm_qkv(const _Float16* __restrict__ Xb,
                                                const _Float16* __restrict__ Wb,
                                                const float* __restrict__ b0,
                                                const float* __restrict__ b1,
                                                const float* __restrict__ b2,
                                                _Float16* __restrict__ Pj) {
  const int z = blockIdx.z;
  const _Float16* A = Xb + (size_t)z * MT * DD;
  const _Float16* W = Wb + (size_t)z * DD * DD;
  const float* bias = (z == 0) ? b0 : ((z == 1) ? b1 : b2);
  _Float16* out = Pj + (size_t)z * MT * DD;

  const int m0 = blockIdx.x * 128;   // m fastest -> XCD round-robin over m
  const int n0 = blockIdx.y * 128;
  const int t = threadIdx.x;
  const int lane = t & 63;
  const int wave = t >> 6;
  const int q = lane >> 4, r = lane & 15;
  const int wm = (wave & 1) * 64, wn = (wave >> 1) * 64;

  __shared__ __align__(16) _Float16 sA[128 * 32];
  __shared__ __align__(16) _Float16 sB[128 * 32];

  f32x4 acc[4][4] = {};

  const int row0 = t >> 2, cc = t & 3;
  const int wch = (t & 3) ^ ((t >> 3) & 3);  // write-side chunk swizzle
  const int fsw = (r >> 1) & 3;              // frag-read chunk swizzle

  f16x8 apre[2], bpre[2];

  auto prefetch = [&](int k0) {
#pragma unroll
    for (int i = 0; i < 2; ++i) {
      int row = row0 + 64 * i;
      apre[i] = *(const f16x8*)(A + (size_t)(m0 + row) * DD + k0 + cc * 8);
      bpre[i] = *(const f16x8*)(W + (size_t)(n0 + row) * DD + k0 + cc * 8);
    }
  };

  prefetch(0);

  for (int k0 = 0; k0 < DD; k0 += 32) {
#pragma unroll
    for (int i = 0; i < 2; ++i) {
      int row = row0 + 64 * i;
      *(f16x8*)&sA[row * 32 + wch * 8] = apre[i];
      *(f16x8*)&sB[row * 32 + wch * 8] = bpre[i];
    }
    __syncthreads();
    if (k0 + 32 < DD) prefetch(k0 + 32);

    f16x8 af[4], bf[4];
#pragma unroll
    for (int x = 0; x < 4; ++x) {
      af[x] = *(const f16x8*)&sA[(wm + x * 16 + r) * 32 + ((q ^ fsw) * 8)];
      bf[x] = *(const f16x8*)&sB[(wn + x * 16 + r) * 32 + ((q ^ fsw) * 8)];
    }
#pragma unroll
    for (int mi = 0; mi < 4; ++mi)
#pragma unroll
      for (int ni = 0; ni < 4; ++ni)
        acc[mi][ni] = __builtin_amdgcn_mfma_f32_16x16x32_f16(af[mi], bf[ni], acc[mi][ni], 0, 0, 0);
    __syncthreads();
  }

  // epilogue: C/D layout col=lane&15 (N), row=(lane>>4)*4+reg (M)
  if (z == 2) {
    // V^T, kappa-permuted keys: kappa0 = 4*(mi&1) + 8*q + 32*(mi>>1), +rr contiguous
    int s_tile = (m0 + wm) & 2047;
    int bb2 = (m0 + wm) >> 11;
#pragma unroll
    for (int ni = 0; ni < 4; ++ni) {
      int gn = n0 + wn + ni * 16 + r;
      float bv = bias[gn];
      int hh = gn >> 6, dk = gn & 63;
      size_t base = ((size_t)((bb2 * HH + hh) * DKC + dk)) * SS + s_tile;
#pragma unroll
      for (int mi = 0; mi < 4; ++mi) {
        int kap0 = 4 * (mi & 1) + 8 * q + 32 * (mi >> 1);
        f16x4 o4;
#pragma unroll
        for (int rr = 0; rr < 4; ++rr) o4[rr] = (_Float16)(acc[mi][ni][rr] + bv);
        *(f16x4*)&out[base + kap0] = o4;
      }
    }
  } else {
    // Q,K: sigma(dk)=(dk&15)*4+(dk>>4); dk=ni*16+r -> sigma=r*4+ni contiguous
    int hh = (n0 + wn) >> 6;
    float bv4[4];
#pragma unroll
    for (int ni = 0; ni < 4; ++ni) bv4[ni] = bias[n0 + wn + ni * 16 + r];
#pragma unroll
    for (int mi = 0; mi < 4; ++mi) {
#pragma unroll
      for (int rr = 0; rr < 4; ++rr) {
        int gm = m0 + wm + mi * 16 + q * 4 + rr;
        int bb2 = gm >> 11, s = gm & 2047;
        f16x4 o4;
#pragma unroll
        for (int ni = 0; ni < 4; ++ni) o4[ni] = (_Float16)(acc[mi][ni][rr] + bv4[ni]);
        *(f16x4*)&out[((size_t)((bb2 * HH + hh) * SS + s)) * DKC + r * 4] = o4;
      }
    }
  }
}

// ---------------- flash attention: one (b,h,q-tile of 128) per block ----------------
// R14: SWAPPED QK^T (mfma(K,Q)) -> C/D: M=keys, N=qrows. Lane (q,r) holds
// P[qrow=n*16+r][key=a*16+q*4+reg], 16 keys/lane. With kappa(key) =
// reg + 4*(a&1) + 8*q + 32*(a>>1), those 16 values ARE the lane's PV A-frag
// (element j of half kk = p[a=2kk+(j>>2)][reg=j&3]): P never touches LDS.
// Removes per tile: 8 ds_write_b64 + threadfence + 4 ds_read_b128 + 16 KB sP.
// LDS 36 -> 20 KB. Row sums: 2 lane-local partials, shfl-reduced at epilogue.
// Q/K global buffers are sigma(dk)-permuted by gemm_qkv; both operands read
// position-based so QK^T is invariant (no change to any read here).
__global__ __launch_bounds__(256) void attn(const _Float16* __restrict__ Pj,
                                            const int* __restrict__ mask,
                                            _Float16* __restrict__ Cx) {
  const int qt = blockIdx.x, h = blockIdx.y, bb = blockIdx.z;
  const size_t hoff = ((size_t)(bb * HH + h) * SS) * DKC;
  const _Float16* Qh  = Pj + hoff;
  const _Float16* Kh  = Pj + (size_t)MT * DD + hoff;
  const _Float16* Vth = Pj + (size_t)2 * MT * DD + hoff;  // [DK][tile*64+kappa]
  _Float16* Ch = Cx + hoff;
  const int* mrow = mask + bb * SS;

  const int t = threadIdx.x, lane = t & 63, wave = t >> 6;
  const int q = lane >> 4, r = lane & 15;
  const int qrow0 = qt * 128 + wave * 32;   // each wave owns 32 Q rows

  __shared__ __align__(16) _Float16 sK[64 * 64];      // [key][dk-pos], chunk-xor swizzled
  __shared__ __align__(16) _Float16 sVt[64 * 64];     // [dk][kappa], chunk-xor swizzled
  __shared__ __align__(16) _Float16 sMBh[SS];         // mask bias (0 / -30000), 4 KB

  // stage mask bias once: 2048 entries / 256 threads = 8 each
  {
    int i0 = t * 8;
    i32x4 m0v = *(const i32x4*)(mrow + i0);
    i32x4 m1v = *(const i32x4*)(mrow + i0 + 4);
    f16x8 bvv;
#pragma unroll
    for (int j = 0; j < 4; ++j) {
      bvv[j]     = m0v[j] ? (_Float16)0.0f : (_Float16)(-30000.0f);
      bvv[4 + j] = m1v[j] ? (_Float16)0.0f : (_Float16)(-30000.0f);
    }
    *(f16x8*)&sMBh[i0] = bvv;
  }

  // Q as B-frags (n=qrow=lane&15): same position-based load as before
  f16x8 qf[2][2];   // [n][kk]
#pragma unroll
  for (int n = 0; n < 2; ++n)
#pragma unroll
    for (int kk = 0; kk < 2; ++kk)
      qf[n][kk] = *(const f16x8*)&Qh[(size_t)(qrow0 + n * 16 + r) * DKC + kk * 32 + q * 8];

  float lst[2] = {};              // lane-local partial row sums (qrow n*16+r)
  f32x4 oacc[2][4] = {};

  const float C2 = 0.125f * 1.44269504089f;  // log2(e)/sqrt(DK)

  // staging coords: 256 thr x 2 iters = 64 rows x 8 chunks of 16 B
  const int srow0 = t >> 3, scc = t & 7;

  // prefetch tile 0 into registers
  f16x8 kpre[2], vpre[2];
#pragma unroll
  for (int i = 0; i < 2; ++i) {
    int row = srow0 + 32 * i;
    kpre[i] = *(const f16x8*)(Kh + (size_t)row * DKC + scc * 8);
    vpre[i] = *(const f16x8*)(Vth + (size_t)row * SS + scc * 8);
  }

  for (int kt = 0; kt < SS; kt += 64) {
    // commit prefetched tile to LDS ((row&7) granule xor, conflict-free)
#pragma unroll
    for (int i = 0; i < 2; ++i) {
      int row = srow0 + 32 * i;
      *(f16x8*)&sK [row * 64 + ((scc ^ (row & 7)) << 3)] = kpre[i];
      *(f16x8*)&sVt[row * 64 + ((scc ^ (row & 7)) << 3)] = vpre[i];
    }
    __syncthreads();   // also covers sMBh visibility on first iteration

    // issue next tile's global loads; vmcnt drains at the NEXT commit
    if (kt + 64 < SS) {
#pragma unroll
      for (int i = 0; i < 2; ++i) {
        int row = srow0 + 32 * i;
        kpre[i] = *(const f16x8*)(Kh + (size_t)(kt + 64 + row) * DKC + scc * 8);
        vpre[i] = *(const f16x8*)(Vth + (size_t)row * SS + kt + 64 + scc * 8);
      }
    }

    // scores = K @ Q^T (swapped): sacc[a][n], value reg -> key a*16+q*4+reg, qrow n*16+r
    f32x4 sacc[4][2] = {};
#pragma unroll
    for (int kk = 0; kk < 2; ++kk) {
      f16x8 kb[4];
#pragma unroll
      for (int a = 0; a < 4; ++a)
        kb[a] = *(const f16x8*)&sK[(a * 16 + r) * 64 + (((kk * 4 + q) ^ (r & 7)) << 3)];
      __builtin_amdgcn_s_setprio(1);
#pragma unroll
      for (int a = 0; a < 4; ++a)
#pragma unroll
        for (int n = 0; n < 2; ++n)
          sacc[a][n] = __builtin_amdgcn_mfma_f32_16x16x32_f16(kb[a], qf[n][kk], sacc[a][n], 0, 0, 0);
      __builtin_amdgcn_s_setprio(0);
    }

    // mask bias for this lane's keys: key = kt + a*16 + q*4 + reg
    f16x4 mbv[4];
#pragma unroll
    for (int a = 0; a < 4; ++a)
      mbv[a] = *(const f16x4*)&sMBh[kt + a * 16 + q * 4];

    // p = exp2(s*C2 + mb); pack in-register into PV A-frags:
    // ap[n][kk] element j = p[a=2kk+(j>>2)][n][reg=j&3]
    unsigned pw[2][2][4];
#pragma unroll
    for (int n = 0; n < 2; ++n) {
#pragma unroll
      for (int a = 0; a < 4; ++a) {
        float pp[4];
#pragma unroll
        for (int reg = 0; reg < 4; ++reg)
          pp[reg] = __builtin_amdgcn_exp2f(__builtin_fmaf(sacc[a][n][reg], C2, (float)mbv[a][reg]));
        lst[n] += (pp[0] + pp[1]) + (pp[2] + pp[3]);
        pw[n][a >> 1][(a & 1) * 2]     = __builtin_bit_cast(unsigned, __builtin_amdgcn_cvt_pkrtz(pp[0], pp[1]));
        pw[n][a >> 1][(a & 1) * 2 + 1] = __builtin_bit_cast(unsigned, __builtin_amdgcn_cvt_pkrtz(pp[2], pp[3]));
      }
    }

    // O += P @ V (contraction over kappa; P frags in registers, V rows at kappa)
#pragma unroll
    for (int kk = 0; kk < 2; ++kk) {
      f16x8 vb[4];
#pragma unroll
      for (int ni = 0; ni < 4; ++ni)
        vb[ni] = *(const f16x8*)&sVt[(ni * 16 + r) * 64 + (((kk * 4 + q) ^ (r & 7)) << 3)];
      __builtin_amdgcn_s_setprio(1);
#pragma unroll
      for (int n = 0; n < 2; ++n) {
        u32x4 w = { pw[n][kk][0], pw[n][kk][1], pw[n][kk][2], pw[n][kk][3] };
        f16x8 apn = __builtin_bit_cast(f16x8, w);
#pragma unroll
        for (int ni = 0; ni < 4; ++ni)
          oacc[n][ni] = __builtin_amdgcn_mfma_f32_16x16x32_f16(apn, vb[ni], oacc[n][ni], 0, 0, 0);
      }
      __builtin_amdgcn_s_setprio(0);
    }
    __syncthreads();
  }

  // epilogue: full row sums = reduce partials over the 4 q-groups (xor 16,32)
  float rinv[2];
#pragma unroll
  for (int n = 0; n < 2; ++n) {
    float l = lst[n];
    l += __shfl_xor(l, 16);
    l += __shfl_xor(l, 32);
    rinv[n] = 1.0f / l;    // lane (q,r): rowsum for qrow n*16+r
  }
  // O rows are indexed q*4+rr -> fetch rinv from lane r'=q*4+rr
  float rn[2][4];
#pragma unroll
  for (int n = 0; n < 2; ++n)
#pragma unroll
    for (int rr = 0; rr < 4; ++rr)
      rn[n][rr] = __shfl(rinv[n], q * 4 + rr);

#pragma unroll
  for (int mi = 0; mi < 2; ++mi)
#pragma unroll
    for (int ni = 0; ni < 4; ++ni)
#pragma unroll
      for (int rr = 0; rr < 4; ++rr) {
        int row = qrow0 + mi * 16 + q * 4 + rr;
        Ch[(size_t)row * DKC + ni * 16 + r] = (_Float16)(oacc[mi][ni][rr] * rn[mi][rr]);
      }
}

// ---------------- output projection: out = ctx @ Wo^T + bo (fp32 out) ----------------
// R14: exact R0 main-loop structure (BM=128, reg-staged f16, 16 KB LDS) +
// conflict-free chunk swizzle. ctx dk is physical (attn O epilogue unchanged).
__global__ __launch_bounds__(256) void gemm_out(const _Float16* __restrict__ Cx,
                                                const _Float16* __restrict__ W,
                                                const float* __restrict__ bias,
                                                float* __restrict__ out) {
  const int m0 = blockIdx.x * 128;
  const int n0 = blockIdx.y * 128;
  const int t = threadIdx.x;
  const int lane = t & 63;
  const int wave = t >> 6;
  const int q = lane >> 4, r = lane & 15;
  const int wm = (wave & 1) * 64, wn = (wave >> 1) * 64;

  __shared__ __align__(16) _Float16 sA[128 * 32];
  __shared__ __align__(16) _Float16 sB[128 * 32];

  f32x4 acc[4][4] = {};

  const int row0 = t >> 2, cc = t & 3;
  const int wch = (t & 3) ^ ((t >> 3) & 3);
  const int fsw = (r >> 1) & 3;

  size_t abase[2];
#pragma unroll
  for (int i = 0; i < 2; ++i) {
    int gm = m0 + row0 + 64 * i;
    int bb = gm >> 11, s = gm & 2047;
    abase[i] = ((size_t)(bb * HH) * SS + s) * DKC;
  }

  f16x8 apre[2], bpre[2];

  auto prefetch = [&](int k0) {
    int head = k0 >> 6, off = (k0 & 63) + cc * 8;
#pragma unroll
    for (int i = 0; i < 2; ++i) {
      apre[i] = *(const f16x8*)(Cx + abase[i] + (size_t)head * SS * DKC + off);
      bpre[i] = *(const f16x8*)(W + (size_t)(n0 + row0 + 64 * i) * DD + k0 + cc * 8);
    }
  };

  prefetch(0);

  for (int k0 = 0; k0 < DD; k0 += 32) {
#pragma unroll
    for (int i = 0; i < 2; ++i) {
      int row = row0 + 64 * i;
      *(f16x8*)&sA[row * 32 + wch * 8] = apre[i];
      *(f16x8*)&sB[row * 32 + wch * 8] = bpre[i];
    }
    __syncthreads();
    if (k0 + 32 < DD) prefetch(k0 + 32);

    f16x8 af[4], bf[4];
#pragma unroll
    for (int x = 0; x < 4; ++x) {
      af[x] = *(const f16x8*)&sA[(wm + x * 16 + r) * 32 + ((q ^ fsw) * 8)];
      bf[x] = *(const f16x8*)&sB[(wn + x * 16 + r) * 32 + ((q ^ fsw) * 8)];
    }
#pragma unroll
    for (int mi = 0; mi < 4; ++mi)
#pragma unroll
      for (int ni = 0; ni < 4; ++ni)
        acc[mi][ni] = __builtin_amdgcn_mfma_f32_16x16x32_f16(af[mi], bf[ni], acc[mi][ni], 0, 0, 0);
    __syncthreads();
  }

#pragma unroll
  for (int ni = 0; ni < 4; ++ni) {
    int gn = n0 + wn + ni * 16 + r;
    float bv = bias[gn];
#pragma unroll
    for (int mi = 0; mi < 4; ++mi) {
#pragma unroll
      for (int rr = 0; rr < 4; ++rr) {
        int gm = m0 + wm + mi * 16 + q * 4 + rr;
        out[(size_t)gm * DD + gn] = acc[mi][ni][rr] + bv;
      }
    }
  }
}

extern "C" void kernel_launch(void* const* d_in, const int* in_sizes, int n_in,
                              void* d_out, int out_size, void* d_ws, size_t ws_size,
                              hipStream_t stream) {
  const float* query = (const float*)d_in[0];
  const float* key_  = (const float*)d_in[1];
  const float* value = (const float*)d_in[2];
  const int*   mask  = (const int*)d_in[3];
  const float* Wq = (const float*)d_in[4];
  const float* bq = (const float*)d_in[5];
  const float* Wk = (const float*)d_in[6];
  const float* bk = (const float*)d_in[7];
  const float* Wv = (const float*)d_in[8];
  const float* bv = (const float*)d_in[9];
  const float* Wo = (const float*)d_in[10];
  const float* bo = (const float*)d_in[11];
  float* out = (float*)d_out;

  // workspace layout (fp16): X(q,k,v) | W(q,k,v,o) | proj Q,K [B,H,S,DK(sigma)] + Vpi [B,H,DK,S'(kappa)] | ctx
  _Float16* Xb = (_Float16*)d_ws;
  _Float16* Wb = Xb + (size_t)3 * NX;
  _Float16* Pj = Wb + (size_t)4 * NW;
  _Float16* Cx = Pj + (size_t)3 * NX;

  cvt_all<<<(3 * NX + 4 * NW) / 1024, 256, 0, stream>>>(query, key_, value, Wq, Wk, Wv, Wo, Xb);

  gemm_qkv<<<dim3(MT / 128, DD / 128, 3), 256, 0, stream>>>(Xb, Wb, bq, bk, bv, Pj);
  attn<<<dim3(SS / 128, HH, BB), 256, 0, stream>>>(Pj, mask, Cx);
  gemm_out<<<dim3(MT / 128, DD / 128), 256, 0, stream>>>(Cx, Wb + (size_t)3 * NW, bo, out);
}